// Round 6
// baseline (296.289 us; speedup 1.0000x reference)
//
#include <hip/hip_runtime.h>
#include <math.h>

#define HW_   40000      // H*W = 200*200
#define NQ_   40000
#define IMGW  200
#define IMGH  200

typedef __bf16 bf16;
typedef __attribute__((ext_vector_type(4))) __bf16 bf16x4;
typedef __attribute__((ext_vector_type(8))) __bf16 bf16x8;
typedef __attribute__((ext_vector_type(4))) float f32x4;

__device__ __forceinline__ void gload_lds16(const void* g, void* l) {
  __builtin_amdgcn_global_load_lds(
      (const __attribute__((address_space(1))) void*)g,
      (__attribute__((address_space(3))) void*)l, 16, 0, 0);
}

// ---------------------------------------------------------------------------
// Prep: weight cast+transpose only. 896 blocks x 256 = 229376 elements.
// ---------------------------------------------------------------------------
__global__ __launch_bounds__(256) void prep_kernel(
    const float* __restrict__ Wv, const float* __restrict__ Wso,
    const float* __restrict__ Waw, const float* __restrict__ Wo,
    bf16* __restrict__ BtV, bf16* __restrict__ BtOA, bf16* __restrict__ BtO)
{
  int idx = blockIdx.x * 256 + threadIdx.x;
  if (idx < 65536) {
    int k = idx >> 8, n = idx & 255;
    BtV[(size_t)n * 256 + k] = (bf16)Wv[idx];
  } else if (idx < 131072) {
    int j = idx - 65536;
    int k = j >> 7, n = j & 127;
    BtOA[(size_t)n * 512 + k] = (bf16)Wso[j];
  } else if (idx < 163840) {
    int j = idx - 131072;
    int k = j >> 6, n = j & 63;
    BtOA[(size_t)(128 + n) * 512 + k] = (bf16)Waw[j];
  } else if (idx < 229376) {
    int j = idx - 163840;
    int k = j >> 8, n = j & 255;
    BtO[(size_t)n * 256 + k] = (bf16)Wo[j];
  }
}

// ---------------------------------------------------------------------------
// MFMA bf16 GEMM, 64 x BN block (R5 structure, verified):
//  * 64-row tiles -> ~4 blocks/CU, barrier drain overlaps across waves.
//  * LDS slot-swizzle (slot ^= (row>>1)&3 on 16B chunks): 2-way floor.
//    gload_lds paths permute the GLOBAL source chunk, reg paths swizzle the
//    ds_write (both-sides-or-neither rule).
// ASRC 0: A bf16 rows via global_load_lds
// ASRC 1: A fp32 rows (A0/A1 halves when KT=512), reg-convert + ds_write
// ASRC 2: A = 0.5*(A0+A1), both bf16 rows (ms0/ms1 merge), reg + ds_write
// MODE 0: vproj -> bf16 (nbq,h,pix,hd), +bias0
// MODE 1: offaw -> off_g (16,40000,8) +bias0 / aw_g (16,40000,4) +bias1
// MODE 2: out   -> fp32 +bias0 +resid
// ---------------------------------------------------------------------------
template<int KT, int MODE, int BN, int ASRC>
__global__ __launch_bounds__(256) void mfma_gemm_kernel(
    const void* __restrict__ A0, const void* __restrict__ A1,
    const bf16* __restrict__ Bt,
    const float* __restrict__ bias0, const float* __restrict__ bias1,
    const float* __restrict__ resid,
    void* __restrict__ outp, void* __restrict__ outp2, int M)
{
  constexpr int NT16 = BN / 32;        // n-tiles per wave (8 or 6)
  constexpr int BCH  = BN / 64;        // B 16-B chunks per thread (4 or 3)
  constexpr int NIT  = KT / 32;        // K-steps (8 or 16)
  __shared__ bf16 As[2][64 * 32];      // 2 x 4 KB
  __shared__ bf16 Bs[2][BN * 32];      // 2 x 16/12 KB
  const int t    = threadIdx.x;
  const int m0   = blockIdx.x * 64;
  const int w    = t >> 6;
  const int lane = t & 63;
  const int quad = lane >> 4;
  const int l16  = lane & 15;
  const int wm   = (w & 1) * 32;
  const int wn   = (w >> 1) * (BN / 2);

  f32x4 acc[2][NT16] = {};

  // A staging: 1 chunk/thread; local row = t>>2, source kchunk = t&3
  int gmA;
  {
    int gm = m0 + (t >> 2);
    gmA = (gm >= M) ? (M - 1) : gm;
  }
  const int arow = t >> 2;
  const int akey = (arow >> 1) & 3;

  float4 apf[2];      // ASRC=1 staging regs
  bf16x8 ah0, ah1;    // ASRC=2 staging regs

  auto issueB = [&](int it) {
    const int kt  = it * 32;
    const int buf = it & 1;
#pragma unroll
    for (int i = 0; i < BCH; ++i) {
      int c   = i * 256 + t;
      int row = c >> 2;
      int j   = (c & 3) ^ ((row >> 1) & 3);     // source-chunk permutation
      gload_lds16(&Bt[(size_t)row * KT + kt + j * 8], &Bs[buf][c * 8]);
    }
  };

  auto issueA_lds = [&](int it) {               // ASRC 0
    const int kt  = it * 32;
    const int buf = it & 1;
    const bf16* Ap = (const bf16*)A0;
    int j = (t & 3) ^ akey;                     // source-chunk permutation
    gload_lds16(&Ap[(size_t)gmA * 256 + kt + j * 8], &As[buf][t * 8]);
  };

  auto loadA_reg = [&](int it) {                // ASRC 1/2 (linear source)
    const int kt = it * 32;
    if (ASRC == 1) {
      const float* Ap; int col;
      if (KT == 512) { Ap = (kt < 256) ? (const float*)A0 : (const float*)A1; col = kt & 255; }
      else           { Ap = (const float*)A0; col = kt; }
      const float4* s4 = (const float4*)&Ap[(size_t)gmA * 256 + col + (t & 3) * 8];
      apf[0] = s4[0];
      apf[1] = s4[1];
    } else {
      ah0 = *(const bf16x8*)&((const bf16*)A0)[(size_t)gmA * 256 + kt + (t & 3) * 8];
      ah1 = *(const bf16x8*)&((const bf16*)A1)[(size_t)gmA * 256 + kt + (t & 3) * 8];
    }
  };

  auto writeA = [&](int it) {                   // convert + swizzled ds_write
    const int buf = it & 1;
    int j = (t & 3) ^ akey;
    bf16x8 o;
    if (ASRC == 1) {
      o = bf16x8{(bf16)apf[0].x, (bf16)apf[0].y, (bf16)apf[0].z, (bf16)apf[0].w,
                 (bf16)apf[1].x, (bf16)apf[1].y, (bf16)apf[1].z, (bf16)apf[1].w};
    } else {
#pragma unroll
      for (int e = 0; e < 8; ++e)
        o[e] = (bf16)(0.5f * ((float)ah0[e] + (float)ah1[e]));
    }
    *(bf16x8*)&As[buf][arow * 32 + j * 8] = o;
  };

  if (ASRC) { loadA_reg(0); issueB(0); writeA(0); }
  else      { issueA_lds(0); issueB(0); }

#pragma unroll
  for (int it = 0; it < NIT; ++it) {
    __syncthreads();                       // drains tile-it loads/writes
    if (it + 1 < NIT) {                    // overlaps the MFMA block below
      issueB(it + 1);
      if (ASRC) loadA_reg(it + 1); else issueA_lds(it + 1);
    }
    const bf16* as = As[it & 1];
    const bf16* bs = Bs[it & 1];
    bf16x8 af[2], bfr[NT16];
#pragma unroll
    for (int x = 0; x < 2; ++x) {
      int row = wm + x * 16 + l16;
      af[x] = *(const bf16x8*)&as[row * 32 + (quad ^ ((row >> 1) & 3)) * 8];
    }
#pragma unroll
    for (int x = 0; x < NT16; ++x) {
      int row = wn + x * 16 + l16;
      bfr[x] = *(const bf16x8*)&bs[row * 32 + (quad ^ ((row >> 1) & 3)) * 8];
    }
#pragma unroll
    for (int mt = 0; mt < 2; ++mt)
#pragma unroll
      for (int nt = 0; nt < NT16; ++nt)
        acc[mt][nt] = __builtin_amdgcn_mfma_f32_16x16x32_bf16(
            af[mt], bfr[nt], acc[mt][nt], 0, 0, 0);
    if (ASRC && it + 1 < NIT) writeA(it + 1);   // to the free buffer
  }

  // ---- epilogue (D: col = lane&15, row = quad*4 + reg) ----
#pragma unroll
  for (int mt = 0; mt < 2; ++mt) {
#pragma unroll
    for (int r = 0; r < 4; ++r) {
      const int gm = m0 + wm + mt * 16 + quad * 4 + r;
      if (gm >= M) continue;
#pragma unroll
      for (int nt = 0; nt < NT16; ++nt) {
        const int gn = wn + nt * 16 + l16;
        float v = acc[mt][nt][r];
        if (MODE == 0) {
          int nbq = (gm >= HW_) ? 1 : 0;
          int pix = gm - nbq * HW_;
          int h = gn >> 5, hd = gn & 31;
          ((bf16*)outp)[(((size_t)(nbq * 8 + h) * HW_ + pix) << 5) + hd] =
              (bf16)(v + bias0[gn]);
        } else if (MODE == 1) {
          if (gn < 128) {
            int gg = gn >> 3, e = gn & 7;    // g-major: off_g[g][q][8]
            ((bf16*)outp)[((size_t)gg * NQ_ + gm) * 8 + e] = (bf16)(v + bias0[gn]);
          } else {
            int j = gn - 128;
            int gg = j >> 2, e = j & 3;      // g-major: aw_g[g][q][4]
            ((bf16*)outp2)[((size_t)gg * NQ_ + gm) * 4 + e] = (bf16)(v + bias1[j]);
          }
        } else {
          ((float*)outp)[(size_t)gm * 256 + gn] =
              v + bias0[gn] + resid[(size_t)gm * 256 + gn];
        }
      }
    }
  }
}

// ---------------------------------------------------------------------------
// Deform sampling v3:
//  * nbq PHASE-SPLIT: blocks 0..4999 -> nbq=0, 5000..9999 -> nbq=1; h = b&7
//    keeps the XCD pinning. Per-XCD working set = ONE 2.56 MB plane (< 4 MiB
//    L2) + g-major off/aw slices. Partials written to ms0/ms1 (no shfl);
//    the out-GEMM averages them (ASRC=2).
//  * FULL-ILP: all 16 corner loads issued before any consumption (the old
//    p-loop at 56 VGPR serialized them into 4-load groups -> 3 exposed
//    latencies per query).
//  Block = 1 head x 1 nbq x 64 queries x 4 subs; wave = 16 q x 4 sub.
// ---------------------------------------------------------------------------
__global__ __launch_bounds__(256) void deform_attn_kernel(
    const bf16* __restrict__ vws,     // (2,8,40000,32) bf16
    const bf16* __restrict__ off_g,   // (16,40000,8) bf16
    const bf16* __restrict__ aw_g,    // (16,40000,4) bf16
    const float* __restrict__ ref,    // (40000,2)
    bf16* __restrict__ ms0,           // (40000,256) bf16 (nbq=0 partial)
    bf16* __restrict__ ms1)           // (40000,256) bf16 (nbq=1 partial)
{
  const int t    = threadIdx.x;
  const int w    = t >> 6;
  const int lane = t & 63;
  const int b    = blockIdx.x;
  const int nbq  = b / 5000;
  const int bb   = b - nbq * 5000;
  const int h    = bb & 7;                // head pinned to XCD
  const int qc   = bb >> 3;               // 0..624
  const int qi   = lane >> 2;             // 0..15
  const int sub  = lane & 3;
  const int q    = qc * 64 + w * 16 + qi;
  const int g    = h * 2 + nbq;
  bf16* msN = nbq ? ms1 : ms0;

  const float rx = ref[2 * q + 0] * (float)IMGW - 0.5f;
  const float ry = ref[2 * q + 1] * (float)IMGH - 0.5f;

  bf16x4 a4 = *(const bf16x4*)&aw_g[((size_t)g * NQ_ + q) * 4];
  float aa0 = (float)a4[0], aa1 = (float)a4[1], aa2 = (float)a4[2], aa3 = (float)a4[3];
  float mx = fmaxf(fmaxf(aa0, aa1), fmaxf(aa2, aa3));
  float e0 = __expf(aa0 - mx), e1 = __expf(aa1 - mx);
  float e2 = __expf(aa2 - mx), e3 = __expf(aa3 - mx);
  float inv = 1.0f / (e0 + e1 + e2 + e3);
  float w4[4] = {e0 * inv, e1 * inv, e2 * inv, e3 * inv};

  bf16x8 o8 = *(const bf16x8*)&off_g[((size_t)g * NQ_ + q) * 8];

  const bf16* vbase = vws + (((size_t)(nbq * 8 + h) * HW_) << 5) + sub * 8;

  // ---- compute all 16 (weight, addr) and issue all 16 loads up front ----
  float  ww[16];
  bf16x8 v[16];
#pragma unroll
  for (int p = 0; p < 4; ++p) {
    float x = rx + (float)o8[2 * p];
    float y = ry + (float)o8[2 * p + 1];
    float xf = floorf(x), yf = floorf(y);
    int   x0 = (int)xf,   y0 = (int)yf;
    float lx = x - xf,    ly = y - yf;
    int   x1 = x0 + 1,    y1 = y0 + 1;
    float w00 = (1.0f - lx) * (1.0f - ly);
    float w01 = lx * (1.0f - ly);
    float w10 = (1.0f - lx) * ly;
    float w11 = lx * ly;
    if (x0 < 0 || x0 >= IMGW) { w00 = 0.0f; w10 = 0.0f; }
    if (x1 < 0 || x1 >= IMGW) { w01 = 0.0f; w11 = 0.0f; }
    if (y0 < 0 || y0 >= IMGH) { w00 = 0.0f; w01 = 0.0f; }
    if (y1 < 0 || y1 >= IMGH) { w10 = 0.0f; w11 = 0.0f; }
    int xc0 = min(max(x0, 0), IMGW - 1), xc1 = min(max(x1, 0), IMGW - 1);
    int yc0 = min(max(y0, 0), IMGH - 1), yc1 = min(max(y1, 0), IMGH - 1);
    float wp = w4[p];
    ww[4 * p + 0] = wp * w00;
    ww[4 * p + 1] = wp * w01;
    ww[4 * p + 2] = wp * w10;
    ww[4 * p + 3] = wp * w11;
    v[4 * p + 0] = *(const bf16x8*)&vbase[(size_t)(yc0 * IMGW + xc0) << 5];
    v[4 * p + 1] = *(const bf16x8*)&vbase[(size_t)(yc0 * IMGW + xc1) << 5];
    v[4 * p + 2] = *(const bf16x8*)&vbase[(size_t)(yc1 * IMGW + xc0) << 5];
    v[4 * p + 3] = *(const bf16x8*)&vbase[(size_t)(yc1 * IMGW + xc1) << 5];
  }

  float acc[8] = {};
#pragma unroll
  for (int s = 0; s < 16; ++s)
#pragma unroll
    for (int j = 0; j < 8; ++j)
      acc[j] = fmaf(ww[s], (float)v[s][j], acc[j]);

  bf16x8 o;
#pragma unroll
  for (int j = 0; j < 8; ++j) o[j] = (bf16)acc[j];
  *(bf16x8*)&msN[(size_t)q * 256 + h * 32 + sub * 8] = o;
}

extern "C" void kernel_launch(void* const* d_in, const int* in_sizes, int n_in,
                              void* d_out, int out_size, void* d_ws, size_t ws_size,
                              hipStream_t stream) {
  const float* query = (const float*)d_in[0];   // (1, 40000, 256)
  const float* value = (const float*)d_in[1];   // (1, 80000, 256)
  const float* ref   = (const float*)d_in[2];   // (1, 40000, 1, 2)
  const float* Wv  = (const float*)d_in[4];
  const float* bv  = (const float*)d_in[5];
  const float* Wso = (const float*)d_in[6];
  const float* bso = (const float*)d_in[7];
  const float* Waw = (const float*)d_in[8];
  const float* baw = (const float*)d_in[9];
  const float* Wo  = (const float*)d_in[10];
  const float* bo  = (const float*)d_in[11];
  float* out = (float*)d_out;

  char* p = (char*)d_ws;
  bf16* vws    = (bf16*)p; p += (size_t)2 * 8 * HW_ * 32 * 2;   // 40.96 MB
  bf16* off_g  = (bf16*)p; p += (size_t)16 * NQ_ * 8 * 2;       // 10.24 MB
  bf16* aw_g   = (bf16*)p; p += (size_t)16 * NQ_ * 4 * 2;       //  5.12 MB
  bf16* ms0    = (bf16*)p; p += (size_t)NQ_ * 256 * 2;          // 20.48 MB
  bf16* ms1    = (bf16*)p; p += (size_t)NQ_ * 256 * 2;          // 20.48 MB
  bf16* BtV    = (bf16*)p; p += (size_t)256 * 256 * 2;
  bf16* BtOA   = (bf16*)p; p += (size_t)192 * 512 * 2;
  bf16* BtO    = (bf16*)p; p += (size_t)256 * 256 * 2;

  // weights only (value/query conversion fused into GEMM A-staging)
  prep_kernel<<<896, 256, 0, stream>>>(Wv, Wso, Waw, Wo, BtV, BtOA, BtO);

  // vproj: value fp32 (80000x256) @ (256x256) -> bf16 (2,8,40000,32)
  mfma_gemm_kernel<256, 0, 256, 1><<<1250, 256, 0, stream>>>(
      value, nullptr, BtV, bv, nullptr, nullptr, vws, nullptr, 2 * HW_);
  // offaw: qe = [value[:40000] | query] fp32 (40000x512) @ (512x192)
  mfma_gemm_kernel<512, 1, 192, 1><<<625, 256, 0, stream>>>(
      value, query, BtOA, bso, baw, nullptr, off_g, aw_g, NQ_);
  // sampling (nbq phase-split, XCD-partitioned by head)
  deform_attn_kernel<<<10000, 256, 0, stream>>>(vws, off_g, aw_g, ref, ms0, ms1);
  // out: 0.5*(ms0+ms1) (40000x256) @ (256x256) + b + residual
  mfma_gemm_kernel<256, 2, 256, 2><<<625, 256, 0, stream>>>(
      ms0, ms1, BtO, bo, nullptr, query, out, nullptr, NQ_);
}